// Round 2
// baseline (486.604 us; speedup 1.0000x reference)
//
#include <hip/hip_runtime.h>

// ---------------------------------------------------------------------------
// NodeTaskHead: B=8 N=256 M=512 EXT=768 E=1024 H=32 D=32
// R3 (resubmit after infra failure): factor the equivariant term:
//   sum_m p*r*(pos_nc - apos_mc)*v = pos_nc*(PR@V) - PR@(apos_c . V)
// R[b][n][m]=1/(1+dist) precomputed (head-shared, L2-resident); V'_c=apos_c.V
// precomputed per head. Kills the per-element delta j-loop (sqrt/rcp/f2b x8)
// that made fused_attn VALU-latency-bound. Bias LDS staging replaced by
// direct per-lane loads (removes 4-way LDS bank conflict + 8KB LDS).
// Pipeline: convert -> proj GEMM -> shuffle -> scale_v -> prep_r ->
//           fused_attn -> final GEMM (merged).
// ---------------------------------------------------------------------------

typedef unsigned short u16;
typedef unsigned int u32;
typedef short short8 __attribute__((ext_vector_type(8)));
typedef float float4v __attribute__((ext_vector_type(4)));

#define SCALING 0.17677669529663687f
#define LOG2E 1.4426950408889634f

__device__ __forceinline__ u16 f2b(float f) {
  union { float f; u32 u; } v; v.f = f;
  return (u16)((v.u + 0x7FFFu + ((v.u >> 16) & 1u)) >> 16);
}
__device__ __forceinline__ float b2f(short s) {
  union { u32 u; float f; } v; v.u = ((u32)(u16)s) << 16;
  return v.f;
}
__device__ __forceinline__ float4v mfma16(short8 a, short8 b, float4v c) {
  return __builtin_amdgcn_mfma_f32_16x16x32_bf16(a, b, c, 0, 0, 0);
}
// async global->LDS, 16B per lane; LDS dest is wave-uniform base + lane*16
__device__ __forceinline__ void gll16(const void* g, void* l) {
  __builtin_amdgcn_global_load_lds((const __attribute__((address_space(1))) void*)g,
                                   (__attribute__((address_space(3))) void*)l, 16, 0, 0);
}

// ---------------------------------------------------------------------------
// K1: dtype conversions.
// ---------------------------------------------------------------------------
__global__ __launch_bounds__(256) void convert_kernel(
    const float* __restrict__ x, const float* __restrict__ Wq,
    const float* __restrict__ Wk, const float* __restrict__ Wv,
    const float* __restrict__ Wve, const float* __restrict__ Wo,
    const float* __restrict__ Woe, u16* __restrict__ xb,
    u16* __restrict__ Wcat, u16* __restrict__ Woe_b, u16* __restrict__ Wo_b) {
  const int idx = blockIdx.x * 256 + threadIdx.x;
  const int stride = gridDim.x * 256;
  for (int i = idx; i < 2048 * 1024; i += stride) {
    const int row = i >> 10, e = i & 1023;
    const int b = row >> 8, n = row & 255;
    xb[i] = f2b(x[((size_t)n * 8 + b) * 1024 + e]);
  }
  for (int i = idx; i < 1024 * 1024; i += stride) {
    Wcat[i] = f2b(Wq[i]);
    Wcat[1048576 + i] = f2b(Wk[i]);
    Wcat[2097152 + i] = f2b(Wv[i]);
    Wcat[3145728 + i] = f2b(Wve[i]);
    Woe_b[i] = f2b(Woe[i]);
    Wo_b[i] = f2b(Wo[i]);
  }
}

// ---------------------------------------------------------------------------
// MFMA bf16 GEMM, C[M,N] f32 = A[M,K] @ W[N,K]^T (bf16 row-major).
// 128x128 tile / block. W selected per row-tile (merged epilogue GEMMs).
// ---------------------------------------------------------------------------
__global__ __launch_bounds__(256) void gemm_bt(
    const u16* __restrict__ A, const u16* __restrict__ W_lo,
    const u16* __restrict__ W_hi, int split_row, float* __restrict__ C,
    int Ndim, int Kdim) {
  __shared__ __align__(16) u16 sA[128 * 32];
  __shared__ __align__(16) u16 sB[128 * 32];
  const int tid = threadIdx.x, wave = tid >> 6, lane = tid & 63;
  const int quad = lane >> 4, l15 = lane & 15;
  const int row0 = blockIdx.y * 128, col0 = blockIdx.x * 128;
  const u16* W = (row0 < split_row) ? W_lo : W_hi;
  const int wr = (wave >> 1) * 64, wc = (wave & 1) * 64;
  const int sr = lane >> 2, sc = lane & 3;
  float4v acc[4][4] = {};
  const u16* gA = A + (size_t)row0 * Kdim;
  const u16* gW = W + (size_t)col0 * Kdim;
  for (int k0 = 0; k0 < Kdim; k0 += 32) {
    __syncthreads();
#pragma unroll
    for (int i = 0; i < 2; ++i) {
      const int r = wave * 32 + i * 16 + sr;
      gll16(gA + (size_t)r * Kdim + k0 + sc * 8, (char*)sA + (wave * 32 + i * 16) * 64);
      gll16(gW + (size_t)r * Kdim + k0 + sc * 8, (char*)sB + (wave * 32 + i * 16) * 64);
    }
    __syncthreads();
    short8 af[4], bf[4];
#pragma unroll
    for (int t = 0; t < 4; ++t) {
      af[t] = *(const short8*)(sA + (wr + t * 16 + l15) * 32 + quad * 8);
      bf[t] = *(const short8*)(sB + (wc + t * 16 + l15) * 32 + quad * 8);
    }
#pragma unroll
    for (int tm = 0; tm < 4; ++tm)
#pragma unroll
      for (int tn = 0; tn < 4; ++tn)
        acc[tm][tn] = mfma16(af[tm], bf[tn], acc[tm][tn]);
  }
#pragma unroll
  for (int tm = 0; tm < 4; ++tm)
#pragma unroll
    for (int tn = 0; tn < 4; ++tn)
#pragma unroll
      for (int r = 0; r < 4; ++r) {
        const int row = row0 + wr + tm * 16 + quad * 4 + r;
        const int col = col0 + wc + tn * 16 + l15;
        C[(size_t)row * Ndim + col] = acc[tm][tn][r];
      }
}

// ---------------------------------------------------------------------------
// K3: build per-head bf16 operands from proj [2048][4096] f32.
// ---------------------------------------------------------------------------
__global__ __launch_bounds__(256) void shuffle_kernel(
    const float* __restrict__ proj, const int* __restrict__ outcell,
    u16* __restrict__ qrow, u16* __restrict__ kext,
    u16* __restrict__ vTx, u16* __restrict__ veTx) {
  __shared__ float lds[32 * 129];
  const int mt = blockIdx.x, h = blockIdx.y, b = blockIdx.z;
  const int tid = threadIdx.x;
  const int bh = b * 32 + h;
#pragma unroll 4
  for (int i = 0; i < 16; ++i) {
    const int idx = tid + 256 * i;  // [128 m][32 d]
    const int ml = idx >> 5, d = idx & 31;
    const int m = mt * 128 + ml;
    const int src = (m < 256) ? m : outcell[b * 512 + m - 256];
    const size_t prow = ((size_t)b * 256 + src) * 4096;
    kext[((size_t)bh * 768 + m) * 32 + d] = f2b(proj[prow + 1024 + h * 32 + d]);
    if (m < 256)
      qrow[((size_t)bh * 256 + m) * 32 + d] = f2b(proj[prow + h * 32 + d] * SCALING);
  }
  for (int part = 0; part < 2; ++part) {
    const size_t cbase = (part == 0) ? 2048 : 3072;
    u16* dst = (part == 0) ? vTx : veTx;
    __syncthreads();
#pragma unroll 4
    for (int i = 0; i < 16; ++i) {
      const int idx = tid + 256 * i;
      const int ml = idx >> 5, d = idx & 31;
      const int m = mt * 128 + ml;
      const int src = (m < 256) ? m : outcell[b * 512 + m - 256];
      lds[d * 129 + ml] = proj[((size_t)b * 256 + src) * 4096 + cbase + h * 32 + d];
    }
    __syncthreads();
#pragma unroll 4
    for (int i = 0; i < 16; ++i) {
      const int idx = tid + 256 * i;
      const int d = idx >> 7, m2 = idx & 127;
      dst[((size_t)bh * 32 + d) * 768 + mt * 128 + m2] = f2b(lds[d * 129 + m2]);
    }
  }
}

// ---------------------------------------------------------------------------
// K3b: V'_c[bh][d][m] = apos[b][m][c] * vTx[bh][d][m]  (c = x,y,z).
// apos = concat(pos, epos) -- NOT gathered (positions are raw, values are).
// ---------------------------------------------------------------------------
__global__ __launch_bounds__(256) void scale_v_kernel(
    const u16* __restrict__ vTx, const float* __restrict__ pos,
    const float* __restrict__ epos, u16* __restrict__ v0,
    u16* __restrict__ v1, u16* __restrict__ v2) {
  const int bh = blockIdx.x, d = blockIdx.y, b = bh >> 5;
  const size_t base = ((size_t)bh * 32 + d) * 768;
  for (int m = threadIdx.x; m < 768; m += 256) {
    const float f = b2f((short)vTx[base + m]);
    const float* ap = (m < 256) ? (pos + ((size_t)b * 256 + m) * 3)
                                : (epos + ((size_t)b * 512 + (m - 256)) * 3);
    v0[base + m] = f2b(f * ap[0]);
    v1[base + m] = f2b(f * ap[1]);
    v2[base + m] = f2b(f * ap[2]);
  }
}

// ---------------------------------------------------------------------------
// K3c: R[b][n][m] = 1/(1 + |pos_bn - apos_bm|), bf16. Head-shared (3.1 MB).
// ---------------------------------------------------------------------------
__global__ __launch_bounds__(256) void prep_r_kernel(
    const float* __restrict__ pos, const float* __restrict__ epos,
    u16* __restrict__ R) {
  const int bn = blockIdx.x;  // 0..2047
  const int b = bn >> 8;
  const float px = pos[(size_t)bn * 3];
  const float py = pos[(size_t)bn * 3 + 1];
  const float pz = pos[(size_t)bn * 3 + 2];
  for (int m = threadIdx.x; m < 768; m += 256) {
    const float* ap = (m < 256) ? (pos + ((size_t)b * 256 + m) * 3)
                                : (epos + ((size_t)b * 512 + (m - 256)) * 3);
    const float dx = px - ap[0], dy = py - ap[1], dz = pz - ap[2];
    const float dist = __builtin_amdgcn_sqrtf(dx * dx + dy * dy + dz * dz);
    R[(size_t)bn * 768 + m] = f2b(__builtin_amdgcn_rcpf(1.0f + dist));
  }
}

// ---------------------------------------------------------------------------
// K4: fused attention. Grid (nt=4, bh=256); block = 64 q-rows, wave w owns
// rows n0+w*16..+15. Per 32-col tile: S = q@k^T + bias (direct per-lane
// loads) -> p = exp (no-max softmax) -> C->A transpose through wave-private
// LDS -> pr = p * R (one short8 LDS read, head-shared R) -> 12 MFMAs:
//   acc_e += P @Ve ; acc_v += PR@V ; acc_c[c] += PR@V'_c
// Epilogue: vec_c = (pos_nc*acc_v - acc_c)*inv_rowsum; xo = acc_e*inv_rowsum.
// ---------------------------------------------------------------------------
__global__ __launch_bounds__(256) void fused_attn(
    const u16* __restrict__ qrow, const u16* __restrict__ kext,
    const u16* __restrict__ vTx, const u16* __restrict__ veTx,
    const u16* __restrict__ v0Tx, const u16* __restrict__ v1Tx,
    const u16* __restrict__ v2Tx, const u16* __restrict__ Rmat,
    const float* __restrict__ bias, const float* __restrict__ pos,
    u16* __restrict__ xo_acc, u16* __restrict__ vec_acc) {
  __shared__ __align__(16) u16 sQ[64 * 32];
  __shared__ __align__(16) u16 sK[32 * 32];
  __shared__ __align__(16) u16 sV[32 * 32];
  __shared__ __align__(16) u16 sVe[32 * 32];
  __shared__ __align__(16) u16 sV0[32 * 32];
  __shared__ __align__(16) u16 sV1[32 * 32];
  __shared__ __align__(16) u16 sV2[32 * 32];
  __shared__ __align__(16) u16 sR[64 * 32];
  __shared__ __align__(16) u16 sPT[4 * 16 * 40];  // stride 40: pad vs conflicts
  const int nt = blockIdx.x, bh = blockIdx.y, b = bh >> 5, h = bh & 31;
  const int n0 = nt * 64;
  const int tid = threadIdx.x, w = tid >> 6, lane = tid & 63;
  const int quad = lane >> 4, l15 = lane & 15;
  const int sl = lane >> 2, sc8 = (lane & 3) * 8;
  gll16(qrow + ((size_t)bh * 256 + n0 + w * 16 + sl) * 32 + sc8,
        (char*)sQ + w * 1024);
  __syncthreads();
  const short8 qf = *(const short8*)(sQ + (w * 16 + l15) * 32 + quad * 8);
  float4v acc_e[2] = {}, acc_v[2] = {}, acc_c[3][2] = {};
  float rowsum[4] = {0.f, 0.f, 0.f, 0.f};
  const u16* gK = kext + (size_t)bh * (768 * 32);
  const u16* gV = vTx + (size_t)bh * (32 * 768);
  const u16* gVe = veTx + (size_t)bh * (32 * 768);
  const u16* gV0 = v0Tx + (size_t)bh * (32 * 768);
  const u16* gV1 = v1Tx + (size_t)bh * (32 * 768);
  const u16* gV2 = v2Tx + (size_t)bh * (32 * 768);
  const u16* gR = Rmat + ((size_t)b * 256 + n0) * 768;
  const float* gB = bias + ((size_t)bh * 256 + n0) * 768;
  u16* const pt = sPT + w * 640;  // 16 rows x 40 u16, wave-private
  for (int k0 = 0; k0 < 768; k0 += 32) {
    __syncthreads();
    if (w == 0) {
      gll16(gK + (size_t)(k0 + sl) * 32 + sc8, (char*)sK);
      gll16(gK + (size_t)(k0 + 16 + sl) * 32 + sc8, (char*)sK + 1024);
      gll16(gR + (size_t)sl * 768 + k0 + sc8, (char*)sR);
      gll16(gR + (size_t)(16 + sl) * 768 + k0 + sc8, (char*)sR + 1024);
    } else if (w == 1) {
      gll16(gV + (size_t)sl * 768 + k0 + sc8, (char*)sV);
      gll16(gV + (size_t)(16 + sl) * 768 + k0 + sc8, (char*)sV + 1024);
      gll16(gR + (size_t)(32 + sl) * 768 + k0 + sc8, (char*)sR + 2048);
      gll16(gR + (size_t)(48 + sl) * 768 + k0 + sc8, (char*)sR + 3072);
    } else if (w == 2) {
      gll16(gVe + (size_t)sl * 768 + k0 + sc8, (char*)sVe);
      gll16(gVe + (size_t)(16 + sl) * 768 + k0 + sc8, (char*)sVe + 1024);
      gll16(gV0 + (size_t)sl * 768 + k0 + sc8, (char*)sV0);
      gll16(gV0 + (size_t)(16 + sl) * 768 + k0 + sc8, (char*)sV0 + 1024);
    } else {
      gll16(gV1 + (size_t)sl * 768 + k0 + sc8, (char*)sV1);
      gll16(gV1 + (size_t)(16 + sl) * 768 + k0 + sc8, (char*)sV1 + 1024);
      gll16(gV2 + (size_t)sl * 768 + k0 + sc8, (char*)sV2);
      gll16(gV2 + (size_t)(16 + sl) * 768 + k0 + sc8, (char*)sV2 + 1024);
    }
    // bias: direct per-lane loads in C-frag layout (no LDS, no bank conflict)
    float bb[4][2];
#pragma unroll
    for (int r = 0; r < 4; ++r) {
      const float* bp = gB + (size_t)(w * 16 + quad * 4 + r) * 768 + k0;
      bb[r][0] = bp[l15];
      bb[r][1] = bp[16 + l15];
    }
    __syncthreads();
    const short8 kf0 = *(const short8*)(sK + l15 * 32 + quad * 8);
    const short8 kf1 = *(const short8*)(sK + (16 + l15) * 32 + quad * 8);
    float4v z = {0.f, 0.f, 0.f, 0.f};
    const float4v s0 = mfma16(qf, kf0, z);
    const float4v s1 = mfma16(qf, kf1, z);
#pragma unroll
    for (int r = 0; r < 4; ++r) {
      const int row = quad * 4 + r;
      const float p0 = exp2f((s0[r] + bb[r][0]) * LOG2E);
      const float p1 = exp2f((s1[r] + bb[r][1]) * LOG2E);
      rowsum[r] += p0 + p1;
      pt[row * 40 + l15] = f2b(p0);
      pt[row * 40 + 16 + l15] = f2b(p1);
    }
    // read back as A-frag (row=l15, k=quad*8+j); same-wave LDS, lgkm-ordered
    const short8 pf = *(const short8*)(pt + l15 * 40 + quad * 8);
    const short8 rf = *(const short8*)(sR + (w * 16 + l15) * 32 + quad * 8);
    short8 prf;
#pragma unroll
    for (int j = 0; j < 8; ++j)
      prf[j] = (short)f2b(b2f(pf[j]) * b2f(rf[j]));
#pragma unroll
    for (int dt = 0; dt < 2; ++dt) {
      const short8 be = *(const short8*)(sVe + (dt * 16 + l15) * 32 + quad * 8);
      acc_e[dt] = mfma16(pf, be, acc_e[dt]);
      const short8 bv = *(const short8*)(sV + (dt * 16 + l15) * 32 + quad * 8);
      acc_v[dt] = mfma16(prf, bv, acc_v[dt]);
      const short8 b0 = *(const short8*)(sV0 + (dt * 16 + l15) * 32 + quad * 8);
      acc_c[0][dt] = mfma16(prf, b0, acc_c[0][dt]);
      const short8 b1 = *(const short8*)(sV1 + (dt * 16 + l15) * 32 + quad * 8);
      acc_c[1][dt] = mfma16(prf, b1, acc_c[1][dt]);
      const short8 b2 = *(const short8*)(sV2 + (dt * 16 + l15) * 32 + quad * 8);
      acc_c[2][dt] = mfma16(prf, b2, acc_c[2][dt]);
    }
  }
  // complete row sums (reduce over the 16 lanes of each quad-row group)
  float li[4];
#pragma unroll
  for (int r = 0; r < 4; ++r) {
    float s = rowsum[r];
#pragma unroll
    for (int msk = 1; msk < 16; msk <<= 1) s += __shfl_xor(s, msk, 64);
    li[r] = __builtin_amdgcn_rcpf(s);
  }
#pragma unroll
  for (int r = 0; r < 4; ++r) {
    const int row = n0 + w * 16 + quad * 4 + r;
    const size_t prow = ((size_t)b * 256 + row) * 3;
    const float pxr = pos[prow], pyr = pos[prow + 1], pzr = pos[prow + 2];
#pragma unroll
    for (int dt = 0; dt < 2; ++dt) {
      const int col = dt * 16 + l15;
      xo_acc[((size_t)b * 256 + row) * 1024 + h * 32 + col] =
          f2b(acc_e[dt][r] * li[r]);
      const float vx = (pxr * acc_v[dt][r] - acc_c[0][dt][r]) * li[r];
      const float vy = (pyr * acc_v[dt][r] - acc_c[1][dt][r]) * li[r];
      const float vz = (pzr * acc_v[dt][r] - acc_c[2][dt][r]) * li[r];
      vec_acc[(prow + 0) * 1024 + h * 32 + col] = f2b(vx);
      vec_acc[(prow + 1) * 1024 + h * 32 + col] = f2b(vy);
      vec_acc[(prow + 2) * 1024 + h * 32 + col] = f2b(vz);
    }
  }
}

// ---------------------------------------------------------------------------
// Workspace layout (bytes). Footprint unchanged (109,051,904 B):
// V'0 aliases xb+Wcat (dead after proj GEMM); V'1/V'2/R alias proj (dead
// after shuffle). scale_v/prep_r therefore launch AFTER shuffle.
// ---------------------------------------------------------------------------
static constexpr size_t OFF_XB = 0;                          // 2048*1024*2
static constexpr size_t OFF_WCAT = OFF_XB + 4194304;         // 4096*1024*2
static constexpr size_t OFF_WOEB = OFF_WCAT + 8388608;       // 1024*1024*2
static constexpr size_t OFF_WOB = OFF_WOEB + 2097152;        // 1024*1024*2
static constexpr size_t OFF_PROJ = OFF_WOB + 2097152;        // 2048*4096*4
static constexpr size_t OFF_QROW = OFF_PROJ + 33554432;      // 256bh*256*32*2
static constexpr size_t OFF_KEXT = OFF_QROW + 4194304;       // 256bh*768*32*2
static constexpr size_t OFF_VTX = OFF_KEXT + 12582912;
static constexpr size_t OFF_VETX = OFF_VTX + 12582912;
static constexpr size_t OFF_XOACC = OFF_VETX + 12582912;     // 2048*1024*2
static constexpr size_t OFF_VECACC = OFF_XOACC + 4194304;    // 6144*1024*2
// aliased regions:
static constexpr size_t OFF_V0 = OFF_XB;                     // 12,582,912
static constexpr size_t OFF_V1 = OFF_PROJ;                   // 12,582,912
static constexpr size_t OFF_V2 = OFF_PROJ + 12582912;        // 12,582,912
static constexpr size_t OFF_R = OFF_PROJ + 25165824;         // 2048*768*2

extern "C" void kernel_launch(void* const* d_in, const int* in_sizes, int n_in,
                              void* d_out, int out_size, void* d_ws, size_t ws_size,
                              hipStream_t stream) {
  const float* x = (const float*)d_in[0];
  const float* pos = (const float*)d_in[1];
  const float* epos = (const float*)d_in[2];
  const float* bias = (const float*)d_in[3];
  const int* outcell = (const int*)d_in[6];
  const float* Wq = (const float*)d_in[7];
  const float* Wk = (const float*)d_in[8];
  const float* Wv = (const float*)d_in[9];
  const float* Wve = (const float*)d_in[10];
  const float* Wo = (const float*)d_in[11];
  const float* Woe = (const float*)d_in[12];
  char* ws = (char*)d_ws;
  u16* xb = (u16*)(ws + OFF_XB);
  u16* Wcat = (u16*)(ws + OFF_WCAT);
  u16* Woe_b = (u16*)(ws + OFF_WOEB);
  u16* Wo_b = (u16*)(ws + OFF_WOB);
  float* proj = (float*)(ws + OFF_PROJ);
  u16* qrow = (u16*)(ws + OFF_QROW);
  u16* kext = (u16*)(ws + OFF_KEXT);
  u16* vTx = (u16*)(ws + OFF_VTX);
  u16* veTx = (u16*)(ws + OFF_VETX);
  u16* v0 = (u16*)(ws + OFF_V0);
  u16* v1 = (u16*)(ws + OFF_V1);
  u16* v2 = (u16*)(ws + OFF_V2);
  u16* Rm = (u16*)(ws + OFF_R);
  u16* xo_acc = (u16*)(ws + OFF_XOACC);
  u16* vec_acc = (u16*)(ws + OFF_VECACC);
  float* out = (float*)d_out;

  convert_kernel<<<1024, 256, 0, stream>>>(x, Wq, Wk, Wv, Wve, Wo, Woe,
                                           xb, Wcat, Woe_b, Wo_b);
  gemm_bt<<<dim3(32, 16), 256, 0, stream>>>(xb, Wcat, Wcat, 1 << 30, proj, 4096, 1024);
  shuffle_kernel<<<dim3(6, 32, 8), 256, 0, stream>>>(proj, outcell, qrow, kext, vTx, veTx);
  scale_v_kernel<<<dim3(256, 32), 256, 0, stream>>>(vTx, pos, epos, v0, v1, v2);
  prep_r_kernel<<<2048, 256, 0, stream>>>(pos, epos, Rm);
  fused_attn<<<dim3(4, 256), 256, 0, stream>>>(qrow, kext, vTx, veTx, v0, v1, v2,
                                               Rm, bias, pos, xo_acc, vec_acc);
  gemm_bt<<<dim3(8, 64), 256, 0, stream>>>(xo_acc, Woe_b, Wo_b, 2048, out, 1024, 1024);
}

// Round 7
// 468.780 us; speedup vs baseline: 1.0380x; 1.0380x over previous
//
#include <hip/hip_runtime.h>

// ---------------------------------------------------------------------------
// NodeTaskHead: B=8 N=256 M=512 EXT=768 E=1024 H=32 D=32
// R8: back to the PROVEN-PASSING R3 skeleton (per k-tile: barrier -> stage ->
// barrier -> compute, single-buffered LDS; the 2-phase stage-across-barrier
// variants failed 4/4 under two different mechanisms and are abandoned).
// Latency fix within the safe skeleton: k-tile doubled 32 -> 64 columns:
// half the stage-drain events (24->12), 2x loads in flight per stage
// (8 gll16/wave), drain amortized over 2x compute. Compute body = R3's,
// run twice per staged tile (columns k0+32h).
// Algorithm (R3 factorization, verified passing in Round 2):
//   sum_m p*r*(pos_nc - apos_mc)*v = pos_nc*(PR@V) - PR@(apos_c . V)
// Pipeline: convert -> proj GEMM -> shuffle -> scale_v -> prep_r ->
//           fused_attn -> final GEMM (merged).
// ---------------------------------------------------------------------------

typedef unsigned short u16;
typedef unsigned int u32;
typedef short short8 __attribute__((ext_vector_type(8)));
typedef float float4v __attribute__((ext_vector_type(4)));

#define SCALING 0.17677669529663687f
#define LOG2E 1.4426950408889634f

__device__ __forceinline__ u16 f2b(float f) {
  union { float f; u32 u; } v; v.f = f;
  return (u16)((v.u + 0x7FFFu + ((v.u >> 16) & 1u)) >> 16);
}
__device__ __forceinline__ float b2f(short s) {
  union { u32 u; float f; } v; v.u = ((u32)(u16)s) << 16;
  return v.f;
}
__device__ __forceinline__ float4v mfma16(short8 a, short8 b, float4v c) {
  return __builtin_amdgcn_mfma_f32_16x16x32_bf16(a, b, c, 0, 0, 0);
}
// async global->LDS, 16B per lane; LDS dest is wave-uniform base + lane*16
__device__ __forceinline__ void gll16(const void* g, void* l) {
  __builtin_amdgcn_global_load_lds((const __attribute__((address_space(1))) void*)g,
                                   (__attribute__((address_space(3))) void*)l, 16, 0, 0);
}

// ---------------------------------------------------------------------------
// K1: dtype conversions.
// ---------------------------------------------------------------------------
__global__ __launch_bounds__(256) void convert_kernel(
    const float* __restrict__ x, const float* __restrict__ Wq,
    const float* __restrict__ Wk, const float* __restrict__ Wv,
    const float* __restrict__ Wve, const float* __restrict__ Wo,
    const float* __restrict__ Woe, u16* __restrict__ xb,
    u16* __restrict__ Wcat, u16* __restrict__ Woe_b, u16* __restrict__ Wo_b) {
  const int idx = blockIdx.x * 256 + threadIdx.x;
  const int stride = gridDim.x * 256;
  for (int i = idx; i < 2048 * 1024; i += stride) {
    const int row = i >> 10, e = i & 1023;
    const int b = row >> 8, n = row & 255;
    xb[i] = f2b(x[((size_t)n * 8 + b) * 1024 + e]);
  }
  for (int i = idx; i < 1024 * 1024; i += stride) {
    Wcat[i] = f2b(Wq[i]);
    Wcat[1048576 + i] = f2b(Wk[i]);
    Wcat[2097152 + i] = f2b(Wv[i]);
    Wcat[3145728 + i] = f2b(Wve[i]);
    Woe_b[i] = f2b(Woe[i]);
    Wo_b[i] = f2b(Wo[i]);
  }
}

// ---------------------------------------------------------------------------
// MFMA bf16 GEMM, C[M,N] f32 = A[M,K] @ W[N,K]^T (bf16 row-major).
// 128x128 tile / block. W selected per row-tile (merged epilogue GEMMs).
// ---------------------------------------------------------------------------
__global__ __launch_bounds__(256) void gemm_bt(
    const u16* __restrict__ A, const u16* __restrict__ W_lo,
    const u16* __restrict__ W_hi, int split_row, float* __restrict__ C,
    int Ndim, int Kdim) {
  __shared__ __align__(16) u16 sA[128 * 32];
  __shared__ __align__(16) u16 sB[128 * 32];
  const int tid = threadIdx.x, wave = tid >> 6, lane = tid & 63;
  const int quad = lane >> 4, l15 = lane & 15;
  const int row0 = blockIdx.y * 128, col0 = blockIdx.x * 128;
  const u16* W = (row0 < split_row) ? W_lo : W_hi;
  const int wr = (wave >> 1) * 64, wc = (wave & 1) * 64;
  const int sr = lane >> 2, sc = lane & 3;
  float4v acc[4][4] = {};
  const u16* gA = A + (size_t)row0 * Kdim;
  const u16* gW = W + (size_t)col0 * Kdim;
  for (int k0 = 0; k0 < Kdim; k0 += 32) {
    __syncthreads();
#pragma unroll
    for (int i = 0; i < 2; ++i) {
      const int r = wave * 32 + i * 16 + sr;
      gll16(gA + (size_t)r * Kdim + k0 + sc * 8, (char*)sA + (wave * 32 + i * 16) * 64);
      gll16(gW + (size_t)r * Kdim + k0 + sc * 8, (char*)sB + (wave * 32 + i * 16) * 64);
    }
    __syncthreads();
    short8 af[4], bf[4];
#pragma unroll
    for (int t = 0; t < 4; ++t) {
      af[t] = *(const short8*)(sA + (wr + t * 16 + l15) * 32 + quad * 8);
      bf[t] = *(const short8*)(sB + (wc + t * 16 + l15) * 32 + quad * 8);
    }
#pragma unroll
    for (int tm = 0; tm < 4; ++tm)
#pragma unroll
      for (int tn = 0; tn < 4; ++tn)
        acc[tm][tn] = mfma16(af[tm], bf[tn], acc[tm][tn]);
  }
#pragma unroll
  for (int tm = 0; tm < 4; ++tm)
#pragma unroll
    for (int tn = 0; tn < 4; ++tn)
#pragma unroll
      for (int r = 0; r < 4; ++r) {
        const int row = row0 + wr + tm * 16 + quad * 4 + r;
        const int col = col0 + wc + tn * 16 + l15;
        C[(size_t)row * Ndim + col] = acc[tm][tn][r];
      }
}

// ---------------------------------------------------------------------------
// K3: build per-head bf16 operands from proj [2048][4096] f32.
// ---------------------------------------------------------------------------
__global__ __launch_bounds__(256) void shuffle_kernel(
    const float* __restrict__ proj, const int* __restrict__ outcell,
    u16* __restrict__ qrow, u16* __restrict__ kext,
    u16* __restrict__ vTx, u16* __restrict__ veTx) {
  __shared__ float lds[32 * 129];
  const int mt = blockIdx.x, h = blockIdx.y, b = blockIdx.z;
  const int tid = threadIdx.x;
  const int bh = b * 32 + h;
#pragma unroll 4
  for (int i = 0; i < 16; ++i) {
    const int idx = tid + 256 * i;  // [128 m][32 d]
    const int ml = idx >> 5, d = idx & 31;
    const int m = mt * 128 + ml;
    const int src = (m < 256) ? m : outcell[b * 512 + m - 256];
    const size_t prow = ((size_t)b * 256 + src) * 4096;
    kext[((size_t)bh * 768 + m) * 32 + d] = f2b(proj[prow + 1024 + h * 32 + d]);
    if (m < 256)
      qrow[((size_t)bh * 256 + m) * 32 + d] = f2b(proj[prow + h * 32 + d] * SCALING);
  }
  for (int part = 0; part < 2; ++part) {
    const size_t cbase = (part == 0) ? 2048 : 3072;
    u16* dst = (part == 0) ? vTx : veTx;
    __syncthreads();
#pragma unroll 4
    for (int i = 0; i < 16; ++i) {
      const int idx = tid + 256 * i;
      const int ml = idx >> 5, d = idx & 31;
      const int m = mt * 128 + ml;
      const int src = (m < 256) ? m : outcell[b * 512 + m - 256];
      lds[d * 129 + ml] = proj[((size_t)b * 256 + src) * 4096 + cbase + h * 32 + d];
    }
    __syncthreads();
#pragma unroll 4
    for (int i = 0; i < 16; ++i) {
      const int idx = tid + 256 * i;
      const int d = idx >> 7, m2 = idx & 127;
      dst[((size_t)bh * 32 + d) * 768 + mt * 128 + m2] = f2b(lds[d * 129 + m2]);
    }
  }
}

// ---------------------------------------------------------------------------
// K3b: V'_c[bh][d][m] = apos[b][m][c] * vTx[bh][d][m]  (c = x,y,z).
// ---------------------------------------------------------------------------
__global__ __launch_bounds__(256) void scale_v_kernel(
    const u16* __restrict__ vTx, const float* __restrict__ pos,
    const float* __restrict__ epos, u16* __restrict__ v0,
    u16* __restrict__ v1, u16* __restrict__ v2) {
  const int bh = blockIdx.x, d = blockIdx.y, b = bh >> 5;
  const size_t base = ((size_t)bh * 32 + d) * 768;
  for (int m = threadIdx.x; m < 768; m += 256) {
    const float f = b2f((short)vTx[base + m]);
    const float* ap = (m < 256) ? (pos + ((size_t)b * 256 + m) * 3)
                                : (epos + ((size_t)b * 512 + (m - 256)) * 3);
    v0[base + m] = f2b(f * ap[0]);
    v1[base + m] = f2b(f * ap[1]);
    v2[base + m] = f2b(f * ap[2]);
  }
}

// ---------------------------------------------------------------------------
// K3c: R[b][n][m] = 1/(1 + |pos_bn - apos_bm|), bf16. Head-shared (3.1 MB).
// ---------------------------------------------------------------------------
__global__ __launch_bounds__(256) void prep_r_kernel(
    const float* __restrict__ pos, const float* __restrict__ epos,
    u16* __restrict__ R) {
  const int bn = blockIdx.x;  // 0..2047
  const int b = bn >> 8;
  const float px = pos[(size_t)bn * 3];
  const float py = pos[(size_t)bn * 3 + 1];
  const float pz = pos[(size_t)bn * 3 + 2];
  for (int m = threadIdx.x; m < 768; m += 256) {
    const float* ap = (m < 256) ? (pos + ((size_t)b * 256 + m) * 3)
                                : (epos + ((size_t)b * 512 + (m - 256)) * 3);
    const float dx = px - ap[0], dy = py - ap[1], dz = pz - ap[2];
    const float dist = __builtin_amdgcn_sqrtf(dx * dx + dy * dy + dz * dz);
    R[(size_t)bn * 768 + m] = f2b(__builtin_amdgcn_rcpf(1.0f + dist));
  }
}

// ---------------------------------------------------------------------------
// K4: fused attention, R3 skeleton with 64-col k-tiles. Grid (nt=4, bh=256);
// 4 waves x 16 q-rows. Per 64-col tile: barrier -> stage (8 gll16/wave +
// bias->regs) -> barrier -> compute two 32-col halves (R3 body per half).
// LDS: sK[64m][32d], sV*[32d][64m], sR[64n][64m], sPT unchanged. 37,888 B.
// ---------------------------------------------------------------------------
__global__ __launch_bounds__(256) void fused_attn(
    const u16* __restrict__ qrow, const u16* __restrict__ kext,
    const u16* __restrict__ vTx, const u16* __restrict__ veTx,
    const u16* __restrict__ v0Tx, const u16* __restrict__ v1Tx,
    const u16* __restrict__ v2Tx, const u16* __restrict__ Rmat,
    const float* __restrict__ bias, const float* __restrict__ pos,
    u16* __restrict__ xo_acc, u16* __restrict__ vec_acc) {
  __shared__ __align__(16) u16 sK[64 * 32];   // [m_local][d]
  __shared__ __align__(16) u16 sV[32 * 64];   // [d][m_local]
  __shared__ __align__(16) u16 sVe[32 * 64];
  __shared__ __align__(16) u16 sV0[32 * 64];
  __shared__ __align__(16) u16 sV1[32 * 64];
  __shared__ __align__(16) u16 sV2[32 * 64];
  __shared__ __align__(16) u16 sR[64 * 64];   // [n_local][m_local]
  __shared__ __align__(16) u16 sPT[4 * 16 * 40];  // stride 40: pad vs conflicts
  const int nt = blockIdx.x, bh = blockIdx.y, b = bh >> 5, h = bh & 31;
  const int n0 = nt * 64;
  const int tid = threadIdx.x, w = tid >> 6, lane = tid & 63;
  const int quad = lane >> 4, l15 = lane & 15;
  const int sl = lane >> 2, sc8 = (lane & 3) * 8;   // 16-row staging (64B rows)
  const int el = lane >> 3, ec8 = (lane & 7) * 8;   // 8-row staging (128B rows)
  // Q direct to registers (16B/lane, coalesced) -- proven in-bounds
  const short8 qf =
      *(const short8*)(qrow + ((size_t)bh * 256 + n0 + w * 16 + l15) * 32 + quad * 8);
  float4v acc_e[2] = {}, acc_v[2] = {}, acc_c[3][2] = {};
  float rowsum[4] = {0.f, 0.f, 0.f, 0.f};
  const u16* gK = kext + (size_t)bh * (768 * 32);
  const u16* gV = vTx + (size_t)bh * (32 * 768);
  const u16* gVe = veTx + (size_t)bh * (32 * 768);
  const u16* gV0 = v0Tx + (size_t)bh * (32 * 768);
  const u16* gV1 = v1Tx + (size_t)bh * (32 * 768);
  const u16* gV2 = v2Tx + (size_t)bh * (32 * 768);
  const u16* gR = Rmat + ((size_t)b * 256 + n0) * 768;
  const float* gB = bias + ((size_t)bh * 256 + n0) * 768;
  u16* const pt = sPT + w * 640;  // 16 rows x 40 u16, wave-private

  for (int k0 = 0; k0 < 768; k0 += 64) {
    __syncthreads();
    if (w == 0) {
      // K: 64 rows(m) x 32(d); 4 calls x 16 rows
      gll16(gK + (size_t)(k0 + sl) * 32 + sc8, (char*)sK);
      gll16(gK + (size_t)(k0 + 16 + sl) * 32 + sc8, (char*)sK + 1024);
      gll16(gK + (size_t)(k0 + 32 + sl) * 32 + sc8, (char*)sK + 2048);
      gll16(gK + (size_t)(k0 + 48 + sl) * 32 + sc8, (char*)sK + 3072);
      // R rows 0..31 (n) x 64(m); 4 calls x 8 rows
      gll16(gR + (size_t)el * 768 + k0 + ec8, (char*)sR);
      gll16(gR + (size_t)(8 + el) * 768 + k0 + ec8, (char*)sR + 1024);
      gll16(gR + (size_t)(16 + el) * 768 + k0 + ec8, (char*)sR + 2048);
      gll16(gR + (size_t)(24 + el) * 768 + k0 + ec8, (char*)sR + 3072);
    } else if (w == 1) {
      // R rows 32..63
      gll16(gR + (size_t)(32 + el) * 768 + k0 + ec8, (char*)sR + 4096);
      gll16(gR + (size_t)(40 + el) * 768 + k0 + ec8, (char*)sR + 5120);
      gll16(gR + (size_t)(48 + el) * 768 + k0 + ec8, (char*)sR + 6144);
      gll16(gR + (size_t)(56 + el) * 768 + k0 + ec8, (char*)sR + 7168);
      // V: 32 rows(d) x 64(m); 4 calls x 8 rows
      gll16(gV + (size_t)el * 768 + k0 + ec8, (char*)sV);
      gll16(gV + (size_t)(8 + el) * 768 + k0 + ec8, (char*)sV + 1024);
      gll16(gV + (size_t)(16 + el) * 768 + k0 + ec8, (char*)sV + 2048);
      gll16(gV + (size_t)(24 + el) * 768 + k0 + ec8, (char*)sV + 3072);
    } else if (w == 2) {
      gll16(gVe + (size_t)el * 768 + k0 + ec8, (char*)sVe);
      gll16(gVe + (size_t)(8 + el) * 768 + k0 + ec8, (char*)sVe + 1024);
      gll16(gVe + (size_t)(16 + el) * 768 + k0 + ec8, (char*)sVe + 2048);
      gll16(gVe + (size_t)(24 + el) * 768 + k0 + ec8, (char*)sVe + 3072);
      gll16(gV0 + (size_t)el * 768 + k0 + ec8, (char*)sV0);
      gll16(gV0 + (size_t)(8 + el) * 768 + k0 + ec8, (char*)sV0 + 1024);
      gll16(gV0 + (size_t)(16 + el) * 768 + k0 + ec8, (char*)sV0 + 2048);
      gll16(gV0 + (size_t)(24 + el) * 768 + k0 + ec8, (char*)sV0 + 3072);
    } else {
      gll16(gV1 + (size_t)el * 768 + k0 + ec8, (char*)sV1);
      gll16(gV1 + (size_t)(8 + el) * 768 + k0 + ec8, (char*)sV1 + 1024);
      gll16(gV1 + (size_t)(16 + el) * 768 + k0 + ec8, (char*)sV1 + 2048);
      gll16(gV1 + (size_t)(24 + el) * 768 + k0 + ec8, (char*)sV1 + 3072);
      gll16(gV2 + (size_t)el * 768 + k0 + ec8, (char*)sV2);
      gll16(gV2 + (size_t)(8 + el) * 768 + k0 + ec8, (char*)sV2 + 1024);
      gll16(gV2 + (size_t)(16 + el) * 768 + k0 + ec8, (char*)sV2 + 2048);
      gll16(gV2 + (size_t)(24 + el) * 768 + k0 + ec8, (char*)sV2 + 3072);
    }
    // bias: direct per-lane loads, 4 x 16-col chunks (C-frag layout)
    float bb[4][4];
#pragma unroll
    for (int r = 0; r < 4; ++r) {
      const float* bp = gB + (size_t)(w * 16 + quad * 4 + r) * 768 + k0;
      bb[r][0] = bp[l15];
      bb[r][1] = bp[16 + l15];
      bb[r][2] = bp[32 + l15];
      bb[r][3] = bp[48 + l15];
    }
    __syncthreads();
    // two 32-col halves; body identical to R3's per-tile compute
#pragma unroll
    for (int hh = 0; hh < 2; ++hh) {
      const short8 kf0 = *(const short8*)(sK + (hh * 32 + l15) * 32 + quad * 8);
      const short8 kf1 = *(const short8*)(sK + (hh * 32 + 16 + l15) * 32 + quad * 8);
      float4v z = {0.f, 0.f, 0.f, 0.f};
      const float4v s0 = mfma16(qf, kf0, z);
      const float4v s1 = mfma16(qf, kf1, z);
#pragma unroll
      for (int r = 0; r < 4; ++r) {
        const int row = quad * 4 + r;
        const float p0 = exp2f((s0[r] + bb[r][2 * hh]) * LOG2E);
        const float p1 = exp2f((s1[r] + bb[r][2 * hh + 1]) * LOG2E);
        rowsum[r] += p0 + p1;
        pt[row * 40 + l15] = f2b(p0);
        pt[row * 40 + 16 + l15] = f2b(p1);
      }
      // read back as A-frag (same-wave LDS, lgkm-ordered)
      const short8 pf = *(const short8*)(pt + l15 * 40 + quad * 8);
      const short8 rf =
          *(const short8*)(sR + (w * 16 + l15) * 64 + hh * 32 + quad * 8);
      short8 prf;
#pragma unroll
      for (int j = 0; j < 8; ++j)
        prf[j] = (short)f2b(b2f(pf[j]) * b2f(rf[j]));
#pragma unroll
      for (int dt = 0; dt < 2; ++dt) {
        const short8 be =
            *(const short8*)(sVe + (dt * 16 + l15) * 64 + hh * 32 + quad * 8);
        acc_e[dt] = mfma16(pf, be, acc_e[dt]);
        const short8 bv =
            *(const short8*)(sV + (dt * 16 + l15) * 64 + hh * 32 + quad * 8);
        acc_v[dt] = mfma16(prf, bv, acc_v[dt]);
        const short8 c0 =
            *(const short8*)(sV0 + (dt * 16 + l15) * 64 + hh * 32 + quad * 8);
        acc_c[0][dt] = mfma16(prf, c0, acc_c[0][dt]);
        const short8 c1 =
            *(const short8*)(sV1 + (dt * 16 + l15) * 64 + hh * 32 + quad * 8);
        acc_c[1][dt] = mfma16(prf, c1, acc_c[1][dt]);
        const short8 c2 =
            *(const short8*)(sV2 + (dt * 16 + l15) * 64 + hh * 32 + quad * 8);
        acc_c[2][dt] = mfma16(prf, c2, acc_c[2][dt]);
      }
    }
  }

  // complete row sums (reduce over the 16 lanes of each quad-row group)
  float li[4];
#pragma unroll
  for (int r = 0; r < 4; ++r) {
    float s = rowsum[r];
#pragma unroll
    for (int msk = 1; msk < 16; msk <<= 1) s += __shfl_xor(s, msk, 64);
    li[r] = __builtin_amdgcn_rcpf(s);
  }
#pragma unroll
  for (int r = 0; r < 4; ++r) {
    const int row = n0 + w * 16 + quad * 4 + r;
    const size_t prow = ((size_t)b * 256 + row) * 3;
    const float pxr = pos[prow], pyr = pos[prow + 1], pzr = pos[prow + 2];
#pragma unroll
    for (int dt = 0; dt < 2; ++dt) {
      const int col = dt * 16 + l15;
      xo_acc[((size_t)b * 256 + row) * 1024 + h * 32 + col] =
          f2b(acc_e[dt][r] * li[r]);
      const float vx = (pxr * acc_v[dt][r] - acc_c[0][dt][r]) * li[r];
      const float vy = (pyr * acc_v[dt][r] - acc_c[1][dt][r]) * li[r];
      const float vz = (pzr * acc_v[dt][r] - acc_c[2][dt][r]) * li[r];
      vec_acc[(prow + 0) * 1024 + h * 32 + col] = f2b(vx);
      vec_acc[(prow + 1) * 1024 + h * 32 + col] = f2b(vy);
      vec_acc[(prow + 2) * 1024 + h * 32 + col] = f2b(vz);
    }
  }
}

// ---------------------------------------------------------------------------
// Workspace layout (bytes). Footprint unchanged (109,051,904 B):
// V'0 aliases xb+Wcat (dead after proj GEMM); V'1/V'2/R alias proj (dead
// after shuffle). scale_v/prep_r therefore launch AFTER shuffle.
// ---------------------------------------------------------------------------
static constexpr size_t OFF_XB = 0;                          // 2048*1024*2
static constexpr size_t OFF_WCAT = OFF_XB + 4194304;         // 4096*1024*2
static constexpr size_t OFF_WOEB = OFF_WCAT + 8388608;       // 1024*1024*2
static constexpr size_t OFF_WOB = OFF_WOEB + 2097152;        // 1024*1024*2
static constexpr size_t OFF_PROJ = OFF_WOB + 2097152;        // 2048*4096*4
static constexpr size_t OFF_QROW = OFF_PROJ + 33554432;      // 256bh*256*32*2
static constexpr size_t OFF_KEXT = OFF_QROW + 4194304;       // 256bh*768*32*2
static constexpr size_t OFF_VTX = OFF_KEXT + 12582912;
static constexpr size_t OFF_VETX = OFF_VTX + 12582912;
static constexpr size_t OFF_XOACC = OFF_VETX + 12582912;     // 2048*1024*2
static constexpr size_t OFF_VECACC = OFF_XOACC + 4194304;    // 6144*1024*2
// aliased regions:
static constexpr size_t OFF_V0 = OFF_XB;                     // 12,582,912
static constexpr size_t OFF_V1 = OFF_PROJ;                   // 12,582,912
static constexpr size_t OFF_V2 = OFF_PROJ + 12582912;        // 12,582,912
static constexpr size_t OFF_R = OFF_PROJ + 25165824;         // 2048*768*2

extern "C" void kernel_launch(void* const* d_in, const int* in_sizes, int n_in,
                              void* d_out, int out_size, void* d_ws, size_t ws_size,
                              hipStream_t stream) {
  const float* x = (const float*)d_in[0];
  const float* pos = (const float*)d_in[1];
  const float* epos = (const float*)d_in[2];
  const float* bias = (const float*)d_in[3];
  const int* outcell = (const int*)d_in[6];
  const float* Wq = (const float*)d_in[7];
  const float* Wk = (const float*)d_in[8];
  const float* Wv = (const float*)d_in[9];
  const float* Wve = (const float*)d_in[10];
  const float* Wo = (const float*)d_in[11];
  const float* Woe = (const float*)d_in[12];
  char* ws = (char*)d_ws;
  u16* xb = (u16*)(ws + OFF_XB);
  u16* Wcat = (u16*)(ws + OFF_WCAT);
  u16* Woe_b = (u16*)(ws + OFF_WOEB);
  u16* Wo_b = (u16*)(ws + OFF_WOB);
  float* proj = (float*)(ws + OFF_PROJ);
  u16* qrow = (u16*)(ws + OFF_QROW);
  u16* kext = (u16*)(ws + OFF_KEXT);
  u16* vTx = (u16*)(ws + OFF_VTX);
  u16* veTx = (u16*)(ws + OFF_VETX);
  u16* v0 = (u16*)(ws + OFF_V0);
  u16* v1 = (u16*)(ws + OFF_V1);
  u16* v2 = (u16*)(ws + OFF_V2);
  u16* Rm = (u16*)(ws + OFF_R);
  u16* xo_acc = (u16*)(ws + OFF_XOACC);
  u16* vec_acc = (u16*)(ws + OFF_VECACC);
  float* out = (float*)d_out;

  convert_kernel<<<1024, 256, 0, stream>>>(x, Wq, Wk, Wv, Wve, Wo, Woe,
                                           xb, Wcat, Woe_b, Wo_b);
  gemm_bt<<<dim3(32, 16), 256, 0, stream>>>(xb, Wcat, Wcat, 1 << 30, proj, 4096, 1024);
  shuffle_kernel<<<dim3(6, 32, 8), 256, 0, stream>>>(proj, outcell, qrow, kext, vTx, veTx);
  scale_v_kernel<<<dim3(256, 32), 256, 0, stream>>>(vTx, pos, epos, v0, v1, v2);
  prep_r_kernel<<<2048, 256, 0, stream>>>(pos, epos, Rm);
  fused_attn<<<dim3(4, 256), 256, 0, stream>>>(qrow, kext, vTx, veTx, v0, v1, v2,
                                               Rm, bias, pos, xo_acc, vec_acc);
  gemm_bt<<<dim3(8, 64), 256, 0, stream>>>(xo_acc, Woe_b, Wo_b, 2048, out, 1024, 1024);
}